// Round 6
// baseline (26353.036 us; speedup 1.0000x reference)
//
#include <hip/hip_runtime.h>
#include <hip/hip_bf16.h>

#define DEV __device__ __forceinline__

// ---------- full-wave (64-lane) f32 max, result broadcast via readlane 63 ----------
DEV float wave_max_f32(float v) {
#define STEPDPP(ctrl) { int iv = __float_as_int(v); \
    int sh = __builtin_amdgcn_update_dpp(iv, iv, ctrl, 0xf, 0xf, false); \
    v = fmaxf(v, __int_as_float(sh)); }
  STEPDPP(0x111)  // row_shr:1
  STEPDPP(0x112)  // row_shr:2
  STEPDPP(0x114)  // row_shr:4
  STEPDPP(0x118)  // row_shr:8
  STEPDPP(0x142)  // row_bcast:15
  STEPDPP(0x143)  // row_bcast:31
#undef STEPDPP
  return __int_as_float(__builtin_amdgcn_readlane(__float_as_int(v), 63));
}

// u32 variant (rare tie-refinement path only)
DEV unsigned wave_max_u32(unsigned v) {
#define STEPDPPU(ctrl) { unsigned sh = (unsigned)__builtin_amdgcn_update_dpp((int)v, (int)v, ctrl, 0xf, 0xf, false); \
    v = (sh > v) ? sh : v; }
  STEPDPPU(0x111)
  STEPDPPU(0x112)
  STEPDPPU(0x114)
  STEPDPPU(0x118)
  STEPDPPU(0x142)
  STEPDPPU(0x143)
#undef STEPDPPU
  return (unsigned)__builtin_amdgcn_readlane((int)v, 63);
}

// ---------- sentinel: ws too small / input-shape mismatch ----------
__global__ void sentinel_k(float* out) {
  out[0] = 1000.0f;
}

__global__ __launch_bounds__(256) void zero_k(double* __restrict__ p, int n) {
  int i = blockIdx.x * 256 + threadIdx.x;
  if (i < n) p[i] = 0.0;
}

// ---------- FPS phase A: Morton counting sort -> TRANSPOSED float4(x,y,z,orig) ----------
// Morton rank s -> ws4T[(s&15)*Q + (s>>4)]  (Q = NPTS/16 chunks).
// Chunk q = 16 consecutive Morton ranks; element k of chunk q at k*Q+q:
// lane-consecutive ==> coalesced global reads + conflict-free LDS mirror.
// Within-cell order arbitrary (atomics): affects only pruning quality,
// never any computed value or the selection.
template<int NPTS, int STRIDE, int PPG0, int Q>
__global__ __launch_bounds__(512) void fps_sort_k(const float* __restrict__ pts,
                                                  float4* __restrict__ ws4T) {
  static_assert(Q * 16 == NPTS, "layout");
  const int b = blockIdx.x, t = threadIdx.x;
  const int lane = t & 63, wv = t >> 6;
  __shared__ int hist[512];
  __shared__ int base_[512];
  __shared__ int wsum[8];
  const float* Pb = pts + (size_t)b * NPTS * STRIDE;
  for (int i = t; i < 512; i += 512) hist[i] = 0;
  __syncthreads();
  float xx[PPG0], yy[PPG0], zz[PPG0];
  int mc[PPG0];
#pragma unroll
  for (int j = 0; j < PPG0; ++j) {
    int g = t * PPG0 + j;
    float x = Pb[(size_t)g * STRIDE];
    float y = Pb[(size_t)g * STRIDE + 1];
    float z = Pb[(size_t)g * STRIDE + 2];
    xx[j] = x; yy[j] = y; zz[j] = z;
    int ix = (int)(x * 8.0f); ix = ix < 0 ? 0 : (ix > 7 ? 7 : ix);
    int iy = (int)(y * 8.0f); iy = iy < 0 ? 0 : (iy > 7 ? 7 : iy);
    int iz = (int)(z * 8.0f); iz = iz < 0 ? 0 : (iz > 7 ? 7 : iz);
    // 9-bit Morton interleave: contiguous sorted ranges are spatially compact
    int m = ((ix & 1) << 2) | ((iy & 1) << 1) | (iz & 1)
          | (((ix >> 1) & 1) << 5) | (((iy >> 1) & 1) << 4) | (((iz >> 1) & 1) << 3)
          | (((ix >> 2) & 1) << 8) | (((iy >> 2) & 1) << 7) | (((iz >> 2) & 1) << 6);
    mc[j] = m;
    atomicAdd(&hist[m], 1);
  }
  __syncthreads();
  {  // exclusive scan of 512 bins (1 per thread)
    int h = hist[t];
    int inc = h;
    for (int d = 1; d < 64; d <<= 1) {
      int u = __shfl_up(inc, d);
      if (lane >= d) inc += u;
    }
    if (lane == 63) wsum[wv] = inc;
    __syncthreads();
    int off = 0;
#pragma unroll
    for (int w = 0; w < 8; ++w) if (w < wv) off += wsum[w];
    base_[t] = off + inc - h;
  }
  __syncthreads();
#pragma unroll
  for (int j = 0; j < PPG0; ++j) {
    int slot = atomicAdd(&base_[mc[j]], 1);
    int tix = (slot & 15) * Q + (slot >> 4);   // transposed index
    ws4T[(size_t)b * NPTS + tix] =
        make_float4(xx[j], yy[j], zz[j], (float)(t * PPG0 + j));
  }
}

// ---------- FPS phase B: SINGLE-WAVE pruned loop (bit-exact, barrier-free) ----------
// Semantics identical to reference _fps: fp32 distances in np op order
// ((dx*dx+dy*dy)+dz*dz), exact fmin chain, argmax with first-(original)-index
// tie break (min orig at every compare level). A 16-point chunk is rescanned
// only when the f32 conservative bound (slacks 5e-4 / 1e-3 >> all fp32
// rounding ~1e-7 rel) admits a dist change; skipped chunks provably have ALL
// dists unchanged, so cached chunk-bests stay exact and no value ever differs.
// ONE wave: no __syncthreads, no cross-wave reduce, no store drain.
// dist[] in LDS (transposed, conflict-free); chunk bounds/bests in registers;
// coords streamed from the L2-resident sorted float4 array (coalesced).
template<int NPTS, int NPT, int STRIDE, int CH>
__global__ __launch_bounds__(64, 1) void fps_sw2_k(const float* __restrict__ pts,
                                                   const float4* __restrict__ ws4T,
                                                   float* __restrict__ out_xyz,
                                                   float* __restrict__ out_f) {
  constexpr int Q = NPTS / 16;          // total chunks
  static_assert(CH * 64 == Q, "chunk layout");
  __shared__ float dl[NPTS];            // dists, transposed: dl[k*Q + q]
  const int b = blockIdx.x, lane = threadIdx.x;
  const float4* P4 = ws4T + (size_t)b * NPTS;

  float bcx[CH], bcy[CH], bcz[CH], rad[CH], rs2c[CH];
  float bd[CH], bo[CH];
  int bp[CH];

  // ---- init: per-chunk bbox + conservative radius; dist = 1e10 ----
#pragma unroll
  for (int c = 0; c < CH; ++c) {
    const int q = c * 64 + lane;
    float mnx = 1e30f, mny = 1e30f, mnz = 1e30f;
    float mxx = -1e30f, mxy = -1e30f, mxz = -1e30f;
#pragma unroll
    for (int k = 0; k < 16; ++k) {
      float4 v = P4[k * Q + q];
      dl[k * Q + q] = 1e10f;
      mnx = fminf(mnx, v.x); mxx = fmaxf(mxx, v.x);
      mny = fminf(mny, v.y); mxy = fmaxf(mxy, v.y);
      mnz = fminf(mnz, v.z); mxz = fmaxf(mxz, v.z);
    }
    bcx[c] = 0.5f * (mnx + mxx);
    bcy[c] = 0.5f * (mny + mxy);
    bcz[c] = 0.5f * (mnz + mxz);
    float r2 = 0.0f;
#pragma unroll
    for (int k = 0; k < 16; ++k) {
      float4 v = P4[k * Q + q];
      float dx = v.x - bcx[c], dy = v.y - bcy[c], dz = v.z - bcz[c];
      r2 = fmaxf(r2, dx * dx + dy * dy + dz * dz);
    }
    rad[c] = sqrtf(r2) * 1.0005f + 1e-20f;   // chunk radius upper bound
    rs2c[c] = 1e30f;                         // force rescan at s=0
    bd[c] = -1.0f; bo[c] = 0.0f; bp[c] = q;
  }

  // initial centroid = original point 0 (exact input floats; broadcast load)
  const float* Pb = pts + (size_t)b * NPTS * STRIDE;
  float ccx = Pb[0], ccy = Pb[1], ccz = Pb[2];
  if (lane == 0) {
    size_t o = (size_t)b * NPT * 3;
    out_xyz[o] = ccx; out_xyz[o + 1] = ccy; out_xyz[o + 2] = ccz;
    if (out_f) { out_f[o] = ccx; out_f[o + 1] = ccy; out_f[o + 2] = ccz; }
  }

  float lbd = -1.0f, lbo = 0.0f;
  unsigned lblo = 0u;
  int lbp = 0;

  for (int s = 0; s < NPT - 1; ++s) {
    bool dirty = false;
#pragma unroll
    for (int c = 0; c < CH; ++c) {
      float dxc = ccx - bcx[c], dyc = ccy - bcy[c], dzc = ccz - bcz[c];
      bool act = (dxc * dxc + dyc * dyc + dzc * dzc) < rs2c[c];
      if (__ballot(act) != 0ull) {          // wave-uniform slot skip
        if (act) {
          const int q = c * 64 + lane;
          float nbd = -1.0f, nbo = 0.0f;
          int nbp = q;
          {
#pragma clang fp contract(off)
#pragma unroll
            for (int k = 0; k < 16; ++k) {
              const int idx = k * Q + q;
              float4 v = P4[idx];
              float dx = v.x - ccx, dy = v.y - ccy, dz = v.z - ccz;
              float d = (dx * dx + dy * dy) + dz * dz;   // exact np order, no FMA
              float dj = fminf(dl[idx], d);
              dl[idx] = dj;
              bool better = (dj > nbd) || (dj == nbd && v.w < nbo);
              if (better) { nbd = dj; nbo = v.w; nbp = idx; }
            }
          }
          bd[c] = nbd; bo[c] = nbo; bp[c] = nbp;   // nbd == chunk max dist
          float rr = rad[c] + sqrtf(nbd);
          rs2c[c] = rr * rr * 1.001f;              // conservative slack
          dirty = true;
        }
      }
    }
    if (dirty) {   // refresh cached lane best from per-chunk bests
      lbd = bd[0]; lbo = bo[0]; lbp = bp[0];
#pragma unroll
      for (int c = 1; c < CH; ++c) {
        bool bt = (bd[c] > lbd) || (bd[c] == lbd && bo[c] < lbo);
        if (bt) { lbd = bd[c]; lbo = bo[c]; lbp = bp[c]; }
      }
      lblo = 0xFFFFFFFFu - (unsigned)lbo;
    }
    // wave argmax: f32 max, rare min-orig tie refinement
    float wm = wave_max_f32(lbd);
    unsigned long long mk = __ballot(lbd == wm);
    if (mk & (mk - 1)) {                     // tie: max klo == min orig (unique)
      unsigned lom = wave_max_u32((lbd == wm) ? lblo : 0u);
      mk = __ballot(lbd == wm && lblo == lom);
    }
    int wl = __ffsll(mk) - 1;
    int wpos = __shfl(lbp, wl);
    float4 wc = P4[wpos];                    // broadcast load (L1/L2 hit)
    ccx = wc.x; ccy = wc.y; ccz = wc.z;
    if (lane == 0) {                         // fire-and-forget store (no barrier)
      size_t o = ((size_t)b * NPT + s + 1) * 3;
      out_xyz[o] = ccx; out_xyz[o + 1] = ccy; out_xyz[o + 2] = ccz;
      if (out_f) { out_f[o] = ccx; out_f[o + 1] = ccy; out_f[o + 2] = ccz; }
    }
  }
}

// ---------- layer-1 (fp64 compute, fp32 inputs): ball (first 32 asc) + conv ----------
template<bool APPLY>
__global__ __launch_bounds__(256) void ball1_k(
    const float* __restrict__ xyz, const float* __restrict__ l1xyz,
    const float* __restrict__ w1, const float* __restrict__ b1,
    const double* __restrict__ A1, const double* __restrict__ B1,
    float* __restrict__ l1pts,
    double* __restrict__ S1R, double* __restrict__ S2R) {
  const int blk = blockIdx.x;
  const int b = blk >> 11, s = blk & 2047;
  const int t = threadIdx.x;
  __shared__ double w1s[768];
  __shared__ double b1s[128];
  __shared__ unsigned long long wm[4];
  __shared__ int lst[32];
  __shared__ double fls[32][6];
  __shared__ double red0[128], red1[128];

  for (int i = t; i < 768; i += 256) w1s[i] = (double)w1[i];
  if (t < 128) b1s[t] = (double)b1[t];

  const float* xb = xyz + (size_t)b * 8192 * 6;
  size_t co = ((size_t)b * 2048 + s) * 3;
  double cx = (double)l1xyz[co], cy = (double)l1xyz[co+1], cz = (double)l1xyz[co+2];

  const double R2 = 0.0025 * 0.0025;
  int cnt = 0;
  const int wvv = t >> 6, lane = t & 63;
  {
#pragma clang fp contract(off)
    double cs2 = (cx*cx + cy*cy) + cz*cz;
    for (int chunk = 0; chunk < 32 && cnt < 32; ++chunk) {
      int g = chunk * 256 + t;
      double x = (double)xb[(size_t)g*6];
      double y = (double)xb[(size_t)g*6+1];
      double z = (double)xb[(size_t)g*6+2];
      double pn2 = (x*x + y*y) + z*z;
      double dot = (cx*x + cy*y) + cz*z;
      double dsq = (cs2 + pn2) - 2.0 * dot;    // exact ref formula/order
      bool pred = !(dsq > R2);
      unsigned long long m = __ballot(pred);
      if (lane == 0) wm[wvv] = m;
      __syncthreads();
      int pre = 0, tot = 0;
      for (int w = 0; w < 4; ++w) {
        int c = __popcll(wm[w]);
        if (w < wvv) pre += c;
        tot += c;
      }
      if (pred) {
        int rank = cnt + pre + __popcll(m & ((1ull << lane) - 1ull));
        if (rank < 32) lst[rank] = g;
      }
      cnt += tot;
      __syncthreads();
    }
  }
  int cc = cnt < 32 ? cnt : 32;
  if (t >= cc && t < 32) lst[t] = lst[0];   // pad with first (center in own ball)
  __syncthreads();
  if (t < 32) {
    int j = lst[t];
    fls[t][0] = (double)xb[(size_t)j*6]   - cx;
    fls[t][1] = (double)xb[(size_t)j*6+1] - cy;
    fls[t][2] = (double)xb[(size_t)j*6+2] - cz;
    fls[t][3] = (double)xb[(size_t)j*6+3];
    fls[t][4] = (double)xb[(size_t)j*6+4];
    fls[t][5] = (double)xb[(size_t)j*6+5];
  }
  __syncthreads();
  const int d = t & 127, kh = t >> 7;
  if (APPLY) {
    double a = A1[d], bb = B1[d];
    double vmax = -1e300;
    for (int k = kh; k < 32; k += 2) {
      double h = b1s[d];
#pragma unroll
      for (int c = 0; c < 6; ++c) h = fma(fls[k][c], w1s[c*128 + d], h);
      vmax = fmax(vmax, fma(a, h, bb));
    }
    if (kh == 1) red0[d] = vmax;
    __syncthreads();
    if (kh == 0) {
      double v = fmax(vmax, red0[d]);
      l1pts[((size_t)b * 2048 + s) * 128 + d] = (float)fmax(v, 0.0);
    }
  } else {
    double p1 = 0.0, p2 = 0.0;
    for (int k = kh; k < 32; k += 2) {
      double h = b1s[d];
#pragma unroll
      for (int c = 0; c < 6; ++c) h = fma(fls[k][c], w1s[c*128 + d], h);
      p1 += h; p2 = fma(h, h, p2);
    }
    if (kh == 1) { red0[d] = p1; red1[d] = p2; }
    __syncthreads();
    if (kh == 0) {
      int rep = blk & 7;
      atomicAdd(&S1R[(size_t)rep * 128 + d], p1 + red0[d]);
      atomicAdd(&S2R[(size_t)rep * 128 + d], p2 + red1[d]);
    }
  }
}

// ---------- BN finalize (fp64): A=g/sqrt(var+eps), B=be-mu*A ----------
__global__ __launch_bounds__(256) void bn_finalize(const double* __restrict__ S1,
                                                   const double* __restrict__ S2,
                                                   int nrep, int D, double invN,
                                                   const float* __restrict__ g,
                                                   const float* __restrict__ be,
                                                   double* __restrict__ A, double* __restrict__ Bc) {
  int d = blockIdx.x * 256 + threadIdx.x;
  if (d >= D) return;
  double s1 = 0.0, s2 = 0.0;
  for (int r = 0; r < nrep; ++r) {
    s1 += S1[(size_t)r * D + d];
    s2 += S2[(size_t)r * D + d];
  }
  double mu = s1 * invN;
  double var = s2 * invN - mu * mu;
  double a = (double)g[d] / sqrt(var + 1e-5);
  A[d]  = a;
  Bc[d] = (double)be[d] - mu * a;
}

// ---------- layer-2 (fp64): ball (first 16 asc) + conv(131->693); stats / apply ----------
template<bool APPLY>
__global__ __launch_bounds__(256) void ball2_k(
    const float* __restrict__ l1xyz, const float* __restrict__ l1pts,
    const float* __restrict__ l2xyz,
    const float* __restrict__ w2, const float* __restrict__ b2,
    const double* __restrict__ A2, const double* __restrict__ B2,
    float* __restrict__ outp,
    double* __restrict__ T1R, double* __restrict__ T2R) {
  const int blk = blockIdx.x;
  const int b = blk >> 8, s = blk & 255;
  const int t = threadIdx.x;
  __shared__ double fT[131][16];
  __shared__ unsigned long long wm[4];
  __shared__ int lst[16];
  const float* Pb = l1xyz + (size_t)b * 2048 * 3;
  size_t co = ((size_t)b * 256 + s) * 3;
  double cx = (double)l2xyz[co], cy = (double)l2xyz[co+1], cz = (double)l2xyz[co+2];
  const double R2 = 0.005 * 0.005;
  int cnt = 0;
  const int wvv = t >> 6, lane = t & 63;
  {
#pragma clang fp contract(off)
    double cs2 = (cx*cx + cy*cy) + cz*cz;
    for (int chunk = 0; chunk < 8 && cnt < 16; ++chunk) {
      int g = chunk * 256 + t;
      double x = (double)Pb[(size_t)g*3];
      double y = (double)Pb[(size_t)g*3+1];
      double z = (double)Pb[(size_t)g*3+2];
      double pn2 = (x*x + y*y) + z*z;
      double dot = (cx*x + cy*y) + cz*z;
      double dsq = (cs2 + pn2) - 2.0 * dot;
      bool pred = !(dsq > R2);
      unsigned long long m = __ballot(pred);
      if (lane == 0) wm[wvv] = m;
      __syncthreads();
      int pre = 0, tot = 0;
      for (int w = 0; w < 4; ++w) {
        int c = __popcll(wm[w]);
        if (w < wvv) pre += c;
        tot += c;
      }
      if (pred) {
        int rank = cnt + pre + __popcll(m & ((1ull << lane) - 1ull));
        if (rank < 16) lst[rank] = g;
      }
      cnt += tot;
      __syncthreads();
    }
  }
  int cc = cnt < 16 ? cnt : 16;
  if (t >= cc && t < 16) lst[t] = lst[0];
  __syncthreads();
  for (int i = t; i < 16 * 131; i += 256) {
    int k = i & 15, c = i >> 4;
    int j = lst[k];
    double v;
    if (c == 0)      v = (double)Pb[(size_t)j*3]   - cx;
    else if (c == 1) v = (double)Pb[(size_t)j*3+1] - cy;
    else if (c == 2) v = (double)Pb[(size_t)j*3+2] - cz;
    else             v = (double)l1pts[((size_t)b*2048 + j)*128 + (c-3)];
    fT[c][k] = v;
  }
  __syncthreads();
  const int rep = blk & 7;
  for (int dd = 0; dd < 3; ++dd) {
    int d = t + dd * 256;
    if (d >= 693) break;
    double acc[16];
    double bv = (double)b2[d];
#pragma unroll
    for (int k = 0; k < 16; ++k) acc[k] = bv;
    for (int c = 0; c < 131; ++c) {
      double wv2 = (double)w2[(size_t)c * 693 + d];
#pragma unroll
      for (int k = 0; k < 16; ++k) acc[k] = fma(fT[c][k], wv2, acc[k]);
    }
    if (APPLY) {
      double a = A2[d], bb = B2[d];
      double vmax = -1e300;
#pragma unroll
      for (int k = 0; k < 16; ++k) vmax = fmax(vmax, fma(a, acc[k], bb));
      outp[((size_t)b * 256 + s) * 693 + d] = (float)fmax(vmax, 0.0);
    } else {
      double p1 = 0.0, p2 = 0.0;
#pragma unroll
      for (int k = 0; k < 16; ++k) { p1 += acc[k]; p2 = fma(acc[k], acc[k], p2); }
      atomicAdd(&T1R[(size_t)rep * 693 + d], p1);
      atomicAdd(&T2R[(size_t)rep * 693 + d], p2);
    }
  }
}

extern "C" void kernel_launch(void* const* d_in, const int* in_sizes, int n_in,
                              void* d_out, int out_size, void* d_ws, size_t ws_size,
                              hipStream_t stream) {
  (void)out_size;
  float* out = (float*)d_out;   // fp32 outputs (reference returns float32)

  const int want[9] = {196608, 768, 128, 128, 128, 90783, 693, 693, 693};
  bool ok = (n_in == 9);
  for (int i = 0; ok && i < 9; ++i) ok = (in_sizes[i] == want[i]);
  const size_t REQ = 4600000;   // footprint ~4.42 MB (unchanged)
  if (!ok || ws_size < REQ) {
    sentinel_k<<<1, 1, 0, stream>>>(out);
    return;
  }

  const float* xyz = (const float*)d_in[0];
  const float* w1  = (const float*)d_in[1];
  const float* b1  = (const float*)d_in[2];
  const float* g1  = (const float*)d_in[3];
  const float* be1 = (const float*)d_in[4];
  const float* w2  = (const float*)d_in[5];
  const float* b2  = (const float*)d_in[6];
  const float* g2  = (const float*)d_in[7];
  const float* be2 = (const float*)d_in[8];

  // ---- workspace carve (doubles first) ----
  double* S1R = (double*)d_ws;            // 8*128 = 1024
  double* S2R = S1R + 1024;               // 1024
  double* T1R = S2R + 1024;               // 8*693 = 5544
  double* T2R = T1R + 5544;               // 5544
  double* A1  = T2R + 5544;               // 128
  double* B1  = A1 + 128;                 // 128
  double* A2  = B1 + 128;                 // 693
  double* B2  = A2 + 693;                 // 693
  float* l1xyz = (float*)(B2 + 693);      // 4*2048*3 = 24576 f
  float* l2xyz = l1xyz + 24576;           // 4*256*3  = 3072 f
  float* l1pts = l2xyz + 3072;            // 4*2048*128 = 4 MB

  // FPS sorted-coord scratch ALIASES l1pts (fully consumed before ball1<true>
  // writes l1pts). 512KB + 128KB <= 4MB.
  float4* ws4A = (float4*)l1pts;          // 4*8192*16B = 512 KB
  float4* ws4B = ws4A + 4 * 8192;         // 4*2048*16B = 128 KB

  zero_k<<<52, 256, 0, stream>>>(S1R, 13136);

  // FPS: Morton sort (512 thr) then SINGLE-WAVE pruned loop (64 thr, zero
  // barriers, dist in LDS, chunk state in registers).
  fps_sort_k<8192, 6, 16, 512><<<4, 512, 0, stream>>>(xyz, ws4A);
  fps_sw2_k<8192, 2048, 6, 8><<<4, 64, 0, stream>>>(xyz, ws4A, l1xyz, nullptr);
  fps_sort_k<2048, 3, 4, 128><<<4, 512, 0, stream>>>(l1xyz, ws4B);
  fps_sw2_k<2048, 256, 3, 2><<<4, 64, 0, stream>>>(l1xyz, ws4B, l2xyz, out);

  ball1_k<false><<<8192, 256, 0, stream>>>(xyz, l1xyz, w1, b1, nullptr, nullptr,
                                           nullptr, S1R, S2R);
  bn_finalize<<<1, 256, 0, stream>>>(S1R, S2R, 8, 128, 1.0 / (8192.0 * 32.0), g1, be1, A1, B1);
  ball1_k<true><<<8192, 256, 0, stream>>>(xyz, l1xyz, w1, b1, A1, B1,
                                          l1pts, S1R, S2R);

  ball2_k<false><<<1024, 256, 0, stream>>>(l1xyz, l1pts, l2xyz, w2, b2, nullptr, nullptr,
                                           nullptr, T1R, T2R);
  bn_finalize<<<3, 256, 0, stream>>>(T1R, T2R, 8, 693, 1.0 / (1024.0 * 16.0), g2, be2, A2, B2);
  ball2_k<true><<<1024, 256, 0, stream>>>(l1xyz, l1pts, l2xyz, w2, b2, A2, B2,
                                          out + 3072, T1R, T2R);
}

// Round 7
// 5471.476 us; speedup vs baseline: 4.8164x; 4.8164x over previous
//
#include <hip/hip_runtime.h>
#include <hip/hip_bf16.h>

#define DEV __device__ __forceinline__

// ---------- full-wave (64-lane) f32 max, result broadcast via readlane 63 ----------
DEV float wave_max_f32(float v) {
#define STEPDPP(ctrl) { int iv = __float_as_int(v); \
    int sh = __builtin_amdgcn_update_dpp(iv, iv, ctrl, 0xf, 0xf, false); \
    v = fmaxf(v, __int_as_float(sh)); }
  STEPDPP(0x111)  // row_shr:1
  STEPDPP(0x112)  // row_shr:2
  STEPDPP(0x114)  // row_shr:4
  STEPDPP(0x118)  // row_shr:8
  STEPDPP(0x142)  // row_bcast:15
  STEPDPP(0x143)  // row_bcast:31
#undef STEPDPP
  return __int_as_float(__builtin_amdgcn_readlane(__float_as_int(v), 63));
}

// u32 variant (rare tie-refinement path only)
DEV unsigned wave_max_u32(unsigned v) {
#define STEPDPPU(ctrl) { unsigned sh = (unsigned)__builtin_amdgcn_update_dpp((int)v, (int)v, ctrl, 0xf, 0xf, false); \
    v = (sh > v) ? sh : v; }
  STEPDPPU(0x111)
  STEPDPPU(0x112)
  STEPDPPU(0x114)
  STEPDPPU(0x118)
  STEPDPPU(0x142)
  STEPDPPU(0x143)
#undef STEPDPPU
  return (unsigned)__builtin_amdgcn_readlane((int)v, 63);
}

// ---------- sentinel: ws too small / input-shape mismatch ----------
__global__ void sentinel_k(float* out) {
  out[0] = 1000.0f;
}

__global__ __launch_bounds__(256) void zero_k(double* __restrict__ p, int n) {
  int i = blockIdx.x * 256 + threadIdx.x;
  if (i < n) p[i] = 0.0;
}

// ---------- FPS: Morton sort + wave-granular pruned loop (bit-exact) ----------
// Semantics identical to reference _fps: fp32 distances in np op order
// ((dx*dx+dy*dy)+dz*dz), exact fmin chain, argmax with first-(original)-index
// tie break at every compare level. A WAVE skips its rescan only when ALL its
// lanes' f32 conservative bounds (slack 5e-4/1e-3 >> fp32 rounding ~1e-7 rel)
// prove no dist can change -> skips never alter any value. Wave-granular skip
// is the only kind that shortens the barrier-serial critical path (rounds
// 2/5 post-mortems: per-lane exec-masked pruning saves nothing). Morton sort
// makes wave w own one spatial octant so late-stage balls activate 1-2 waves.
// 512 thr, PPG=16 register chunks: proven regalloc-safe (VGPR~100-104).
template<int PPG, int NPT, int NPTS, int STRIDE>
__global__ __launch_bounds__(512) void fps_k(const float* __restrict__ pts,
                                             float* __restrict__ out_xyz,
                                             float* __restrict__ out_f) {
  constexpr int T = 512;
  constexpr int NW = T / 64;            // 8 waves
  static_assert(NPTS == T * PPG, "one chunk per thread");
  const int b = blockIdx.x, t = threadIdx.x;
  const int lane = t & 63, wv = t >> 6;

  __shared__ int perm[NPTS];            // sorted-pos -> original index
  __shared__ int hist[512];
  __shared__ int base_[512];
  __shared__ int wsum[NW];
  __shared__ float4 wkc[2][NW];         // per-wave winner {dist, klo(bits), x, y}
  __shared__ float wz[2][NW];           // per-wave winner z
  __shared__ float ring[128][3];        // batched output ring

  const float* Pb = pts + (size_t)b * NPTS * STRIDE;

  // ---- phase 0: counting sort by Morton cell (order within cell arbitrary;
  //      affects only pruning quality, never values/selection) ----
  for (int i = t; i < 512; i += T) hist[i] = 0;
  __syncthreads();
  int mc[PPG];
#pragma unroll
  for (int j = 0; j < PPG; ++j) {
    int g = t * PPG + j;
    float x = Pb[(size_t)g * STRIDE];
    float y = Pb[(size_t)g * STRIDE + 1];
    float z = Pb[(size_t)g * STRIDE + 2];
    int ix = (int)(x * 8.0f); ix = ix < 0 ? 0 : (ix > 7 ? 7 : ix);
    int iy = (int)(y * 8.0f); iy = iy < 0 ? 0 : (iy > 7 ? 7 : iy);
    int iz = (int)(z * 8.0f); iz = iz < 0 ? 0 : (iz > 7 ? 7 : iz);
    // 9-bit Morton interleave: wave (top 3 bits) = one spatial octant
    int m = ((ix & 1) << 2) | ((iy & 1) << 1) | (iz & 1)
          | (((ix >> 1) & 1) << 5) | (((iy >> 1) & 1) << 4) | (((iz >> 1) & 1) << 3)
          | (((ix >> 2) & 1) << 8) | (((iy >> 2) & 1) << 7) | (((iz >> 2) & 1) << 6);
    mc[j] = m;
    atomicAdd(&hist[m], 1);
  }
  __syncthreads();
  {  // exclusive scan of 512 bins (1 per thread)
    int h = hist[t];
    int inc = h;
    for (int d = 1; d < 64; d <<= 1) {
      int u = __shfl_up(inc, d);
      if (lane >= d) inc += u;
    }
    if (lane == 63) wsum[wv] = inc;
    __syncthreads();
    int off = 0;
#pragma unroll
    for (int w = 0; w < NW; ++w) if (w < wv) off += wsum[w];
    base_[t] = off + inc - h;
  }
  __syncthreads();
#pragma unroll
  for (int j = 0; j < PPG; ++j) {
    int slot = atomicAdd(&base_[mc[j]], 1);
    perm[slot] = t * PPG + j;
  }
  __syncthreads();

  // ---- phase 1: load chunk into REGISTERS; f32 conservative bound ----
  float px[PPG], py[PPG], pz[PPG], dist[PPG], org[PPG];
  float mnx = 1e30f, mny = 1e30f, mnz = 1e30f;
  float mxx = -1e30f, mxy = -1e30f, mxz = -1e30f;
#pragma unroll
  for (int j = 0; j < PPG; ++j) {
    int g = perm[t * PPG + j];
    float x = Pb[(size_t)g * STRIDE];
    float y = Pb[(size_t)g * STRIDE + 1];
    float z = Pb[(size_t)g * STRIDE + 2];
    px[j] = x; py[j] = y; pz[j] = z; dist[j] = 1e10f;
    org[j] = (float)g;                 // exact (g < 2^24)
    mnx = fminf(mnx, x); mxx = fmaxf(mxx, x);
    mny = fminf(mny, y); mxy = fmaxf(mxy, y);
    mnz = fminf(mnz, z); mxz = fmaxf(mxz, z);
  }
  const float bcx = 0.5f * (mnx + mxx);
  const float bcy = 0.5f * (mny + mxy);
  const float bcz = 0.5f * (mnz + mxz);
  float r2 = 0.0f;
#pragma unroll
  for (int j = 0; j < PPG; ++j) {
    float dx = px[j] - bcx, dy = py[j] - bcy, dz = pz[j] - bcz;
    r2 = fmaxf(r2, dx * dx + dy * dy + dz * dz);
  }
  const float rad = sqrtf(r2) * 1.0005f + 1e-20f;   // chunk radius upper bound
  float rs2 = 1e30f;                                // force rescan at s=0

  // cached lane best (valid while this lane's dists are unchanged)
  float lbd = -1.0f, lbo = 3.0e38f, lbx = 0.f, lby = 0.f, lbz = 0.f;
  bool iswin = false;

  // initial centroid = original point 0 (exact input floats; broadcast load)
  float ccx = Pb[0], ccy = Pb[1], ccz = Pb[2];
  if (t == 0) {
    size_t o = (size_t)b * NPT * 3;
    out_xyz[o] = ccx; out_xyz[o + 1] = ccy; out_xyz[o + 2] = ccz;
    if (out_f) { out_f[o] = ccx; out_f[o + 1] = ccy; out_f[o + 2] = ccz; }
  }

  for (int s = 0; s < NPT - 1; ++s) {
    const int p = s & 1;
    float dxc = ccx - bcx, dyc = ccy - bcy, dzc = ccz - bcz;
    bool active = (dxc * dxc + dyc * dyc + dzc * dzc) < rs2;
    unsigned long long mb = __ballot(active);
    if (mb != 0ull) {                  // WAVE-uniform skip (s_cbranch_execz)
      if (active) {
        // two independent half-chains (R0 structure) with exact org tie-break
        float vA = -1.0f, oA = 3.0e38f, axA = 0.f, ayA = 0.f, azA = 0.f;
        float vB = -1.0f, oB = 3.0e38f, axB = 0.f, ayB = 0.f, azB = 0.f;
        {
#pragma clang fp contract(off)
#pragma unroll
          for (int j = 0; j < PPG / 2; ++j) {
            float dx = px[j] - ccx, dy = py[j] - ccy, dz = pz[j] - ccz;
            float d = (dx * dx + dy * dy) + dz * dz;   // exact np order, no FMA
            float dj = fminf(dist[j], d);
            dist[j] = dj;
            bool bt = (dj > vA) || (dj == vA && org[j] < oA);
            if (bt) { vA = dj; oA = org[j]; axA = px[j]; ayA = py[j]; azA = pz[j]; }
          }
#pragma unroll
          for (int j = PPG / 2; j < PPG; ++j) {
            float dx = px[j] - ccx, dy = py[j] - ccy, dz = pz[j] - ccz;
            float d = (dx * dx + dy * dy) + dz * dz;
            float dj = fminf(dist[j], d);
            dist[j] = dj;
            bool bt = (dj > vB) || (dj == vB && org[j] < oB);
            if (bt) { vB = dj; oB = org[j]; axB = px[j]; ayB = py[j]; azB = pz[j]; }
          }
        }
        bool tb = (vB > vA) || (vB == vA && oB < oA);
        lbd = tb ? vB : vA; lbo = tb ? oB : oA;
        lbx = tb ? axB : axA; lby = tb ? ayB : ayA; lbz = tb ? azB : azA;
        float rr = rad + sqrtf(lbd);                  // lbd == chunk max dist
        rs2 = rr * rr * 1.001f;                       // conservative slack
      }
      // reduce only on waves that changed (cached winner else)
      float wm = wave_max_f32(lbd);
      unsigned long long mk = __ballot(lbd == wm);
      if (mk & (mk - 1)) {                            // tie (rare): min orig
        unsigned klo = 0xFFFFFFFFu - (unsigned)lbo;
        unsigned lom = wave_max_u32((lbd == wm) ? klo : 0u);
        iswin = (lbd == wm) && (klo == lom);
      } else {
        iswin = (lbd == wm);
      }
    }
    if (iswin) {                                      // sticky winner refresh
      wkc[p][wv] = make_float4(lbd, __uint_as_float(0xFFFFFFFFu - (unsigned)lbo),
                               lbx, lby);
      wz[p][wv] = lbz;
    }
    __syncthreads();
    // batched output flush (winners j in [s-63, s]); slots disjoint from the
    // concurrent t==0 write to slot (s+1)&127 -> race-free
    if (s >= 64 && (s & 63) == 0 && t < 192) {
      int j = s - 63 + t / 3, c = t % 3;
      float v = ring[j & 127][c];
      size_t o = ((size_t)b * NPT + j) * 3 + c;
      out_xyz[o] = v;
      if (out_f) out_f[o] = v;
    }
    // tree over 8 wave winners ({dist, klo, x, y} + z: one LDS read wave)
    float4 e0 = wkc[p][0], e1 = wkc[p][1], e2 = wkc[p][2], e3 = wkc[p][3];
    float4 e4 = wkc[p][4], e5 = wkc[p][5], e6 = wkc[p][6], e7 = wkc[p][7];
    float z0 = wz[p][0], z1 = wz[p][1], z2 = wz[p][2], z3 = wz[p][3];
    float z4 = wz[p][4], z5 = wz[p][5], z6 = wz[p][6], z7 = wz[p][7];
#define BETTER(A, B) (B.x > A.x || (B.x == A.x && __float_as_uint(B.y) > __float_as_uint(A.y)))
    if (BETTER(e0, e1)) { e0 = e1; z0 = z1; }
    if (BETTER(e2, e3)) { e2 = e3; z2 = z3; }
    if (BETTER(e4, e5)) { e4 = e5; z4 = z5; }
    if (BETTER(e6, e7)) { e6 = e7; z6 = z7; }
    if (BETTER(e0, e2)) { e0 = e2; z0 = z2; }
    if (BETTER(e4, e6)) { e4 = e6; z4 = z6; }
    if (BETTER(e0, e4)) { e0 = e4; z0 = z4; }
#undef BETTER
    ccx = e0.z; ccy = e0.w; ccz = z0;
    if (t == 0) {                                     // winner j = s+1 into ring
      int j = s + 1;
      ring[j & 127][0] = ccx; ring[j & 127][1] = ccy; ring[j & 127][2] = ccz;
    }
  }
  // tail flush: winners after the last in-loop flush
  __syncthreads();
  {
    const int rstart = ((NPT - 2) & ~63) + 1;
    const int nf = ((NPT - 1) - rstart + 1) * 3;
    if (t < nf) {
      int j = rstart + t / 3, c = t % 3;
      float v = ring[j & 127][c];
      size_t o = ((size_t)b * NPT + j) * 3 + c;
      out_xyz[o] = v;
      if (out_f) out_f[o] = v;
    }
  }
}

// ---------- layer-1 (fp64 compute, fp32 inputs): ball (first 32 asc) + conv ----------
template<bool APPLY>
__global__ __launch_bounds__(256) void ball1_k(
    const float* __restrict__ xyz, const float* __restrict__ l1xyz,
    const float* __restrict__ w1, const float* __restrict__ b1,
    const double* __restrict__ A1, const double* __restrict__ B1,
    float* __restrict__ l1pts,
    double* __restrict__ S1R, double* __restrict__ S2R) {
  const int blk = blockIdx.x;
  const int b = blk >> 11, s = blk & 2047;
  const int t = threadIdx.x;
  __shared__ double w1s[768];
  __shared__ double b1s[128];
  __shared__ unsigned long long wm[4];
  __shared__ int lst[32];
  __shared__ double fls[32][6];
  __shared__ double red0[128], red1[128];

  for (int i = t; i < 768; i += 256) w1s[i] = (double)w1[i];
  if (t < 128) b1s[t] = (double)b1[t];

  const float* xb = xyz + (size_t)b * 8192 * 6;
  size_t co = ((size_t)b * 2048 + s) * 3;
  double cx = (double)l1xyz[co], cy = (double)l1xyz[co+1], cz = (double)l1xyz[co+2];

  const double R2 = 0.0025 * 0.0025;
  int cnt = 0;
  const int wvv = t >> 6, lane = t & 63;
  {
#pragma clang fp contract(off)
    double cs2 = (cx*cx + cy*cy) + cz*cz;
    for (int chunk = 0; chunk < 32 && cnt < 32; ++chunk) {
      int g = chunk * 256 + t;
      double x = (double)xb[(size_t)g*6];
      double y = (double)xb[(size_t)g*6+1];
      double z = (double)xb[(size_t)g*6+2];
      double pn2 = (x*x + y*y) + z*z;
      double dot = (cx*x + cy*y) + cz*z;
      double dsq = (cs2 + pn2) - 2.0 * dot;    // exact ref formula/order
      bool pred = !(dsq > R2);
      unsigned long long m = __ballot(pred);
      if (lane == 0) wm[wvv] = m;
      __syncthreads();
      int pre = 0, tot = 0;
      for (int w = 0; w < 4; ++w) {
        int c = __popcll(wm[w]);
        if (w < wvv) pre += c;
        tot += c;
      }
      if (pred) {
        int rank = cnt + pre + __popcll(m & ((1ull << lane) - 1ull));
        if (rank < 32) lst[rank] = g;
      }
      cnt += tot;
      __syncthreads();
    }
  }
  int cc = cnt < 32 ? cnt : 32;
  if (t >= cc && t < 32) lst[t] = lst[0];   // pad with first (center in own ball)
  __syncthreads();
  if (t < 32) {
    int j = lst[t];
    fls[t][0] = (double)xb[(size_t)j*6]   - cx;
    fls[t][1] = (double)xb[(size_t)j*6+1] - cy;
    fls[t][2] = (double)xb[(size_t)j*6+2] - cz;
    fls[t][3] = (double)xb[(size_t)j*6+3];
    fls[t][4] = (double)xb[(size_t)j*6+4];
    fls[t][5] = (double)xb[(size_t)j*6+5];
  }
  __syncthreads();
  const int d = t & 127, kh = t >> 7;
  if (APPLY) {
    double a = A1[d], bb = B1[d];
    double vmax = -1e300;
    for (int k = kh; k < 32; k += 2) {
      double h = b1s[d];
#pragma unroll
      for (int c = 0; c < 6; ++c) h = fma(fls[k][c], w1s[c*128 + d], h);
      vmax = fmax(vmax, fma(a, h, bb));
    }
    if (kh == 1) red0[d] = vmax;
    __syncthreads();
    if (kh == 0) {
      double v = fmax(vmax, red0[d]);
      l1pts[((size_t)b * 2048 + s) * 128 + d] = (float)fmax(v, 0.0);
    }
  } else {
    double p1 = 0.0, p2 = 0.0;
    for (int k = kh; k < 32; k += 2) {
      double h = b1s[d];
#pragma unroll
      for (int c = 0; c < 6; ++c) h = fma(fls[k][c], w1s[c*128 + d], h);
      p1 += h; p2 = fma(h, h, p2);
    }
    if (kh == 1) { red0[d] = p1; red1[d] = p2; }
    __syncthreads();
    if (kh == 0) {
      int rep = blk & 7;
      atomicAdd(&S1R[(size_t)rep * 128 + d], p1 + red0[d]);
      atomicAdd(&S2R[(size_t)rep * 128 + d], p2 + red1[d]);
    }
  }
}

// ---------- BN finalize (fp64): A=g/sqrt(var+eps), B=be-mu*A ----------
__global__ __launch_bounds__(256) void bn_finalize(const double* __restrict__ S1,
                                                   const double* __restrict__ S2,
                                                   int nrep, int D, double invN,
                                                   const float* __restrict__ g,
                                                   const float* __restrict__ be,
                                                   double* __restrict__ A, double* __restrict__ Bc) {
  int d = blockIdx.x * 256 + threadIdx.x;
  if (d >= D) return;
  double s1 = 0.0, s2 = 0.0;
  for (int r = 0; r < nrep; ++r) {
    s1 += S1[(size_t)r * D + d];
    s2 += S2[(size_t)r * D + d];
  }
  double mu = s1 * invN;
  double var = s2 * invN - mu * mu;
  double a = (double)g[d] / sqrt(var + 1e-5);
  A[d]  = a;
  Bc[d] = (double)be[d] - mu * a;
}

// ---------- layer-2 (fp64): ball (first 16 asc) + conv(131->693); stats / apply ----------
template<bool APPLY>
__global__ __launch_bounds__(256) void ball2_k(
    const float* __restrict__ l1xyz, const float* __restrict__ l1pts,
    const float* __restrict__ l2xyz,
    const float* __restrict__ w2, const float* __restrict__ b2,
    const double* __restrict__ A2, const double* __restrict__ B2,
    float* __restrict__ outp,
    double* __restrict__ T1R, double* __restrict__ T2R) {
  const int blk = blockIdx.x;
  const int b = blk >> 8, s = blk & 255;
  const int t = threadIdx.x;
  __shared__ double fT[131][16];
  __shared__ unsigned long long wm[4];
  __shared__ int lst[16];
  const float* Pb = l1xyz + (size_t)b * 2048 * 3;
  size_t co = ((size_t)b * 256 + s) * 3;
  double cx = (double)l2xyz[co], cy = (double)l2xyz[co+1], cz = (double)l2xyz[co+2];
  const double R2 = 0.005 * 0.005;
  int cnt = 0;
  const int wvv = t >> 6, lane = t & 63;
  {
#pragma clang fp contract(off)
    double cs2 = (cx*cx + cy*cy) + cz*cz;
    for (int chunk = 0; chunk < 8 && cnt < 16; ++chunk) {
      int g = chunk * 256 + t;
      double x = (double)Pb[(size_t)g*3];
      double y = (double)Pb[(size_t)g*3+1];
      double z = (double)Pb[(size_t)g*3+2];
      double pn2 = (x*x + y*y) + z*z;
      double dot = (cx*x + cy*y) + cz*z;
      double dsq = (cs2 + pn2) - 2.0 * dot;
      bool pred = !(dsq > R2);
      unsigned long long m = __ballot(pred);
      if (lane == 0) wm[wvv] = m;
      __syncthreads();
      int pre = 0, tot = 0;
      for (int w = 0; w < 4; ++w) {
        int c = __popcll(wm[w]);
        if (w < wvv) pre += c;
        tot += c;
      }
      if (pred) {
        int rank = cnt + pre + __popcll(m & ((1ull << lane) - 1ull));
        if (rank < 16) lst[rank] = g;
      }
      cnt += tot;
      __syncthreads();
    }
  }
  int cc = cnt < 16 ? cnt : 16;
  if (t >= cc && t < 16) lst[t] = lst[0];
  __syncthreads();
  for (int i = t; i < 16 * 131; i += 256) {
    int k = i & 15, c = i >> 4;
    int j = lst[k];
    double v;
    if (c == 0)      v = (double)Pb[(size_t)j*3]   - cx;
    else if (c == 1) v = (double)Pb[(size_t)j*3+1] - cy;
    else if (c == 2) v = (double)Pb[(size_t)j*3+2] - cz;
    else             v = (double)l1pts[((size_t)b*2048 + j)*128 + (c-3)];
    fT[c][k] = v;
  }
  __syncthreads();
  const int rep = blk & 7;
  for (int dd = 0; dd < 3; ++dd) {
    int d = t + dd * 256;
    if (d >= 693) break;
    double acc[16];
    double bv = (double)b2[d];
#pragma unroll
    for (int k = 0; k < 16; ++k) acc[k] = bv;
    for (int c = 0; c < 131; ++c) {
      double wv2 = (double)w2[(size_t)c * 693 + d];
#pragma unroll
      for (int k = 0; k < 16; ++k) acc[k] = fma(fT[c][k], wv2, acc[k]);
    }
    if (APPLY) {
      double a = A2[d], bb = B2[d];
      double vmax = -1e300;
#pragma unroll
      for (int k = 0; k < 16; ++k) vmax = fmax(vmax, fma(a, acc[k], bb));
      outp[((size_t)b * 256 + s) * 693 + d] = (float)fmax(vmax, 0.0);
    } else {
      double p1 = 0.0, p2 = 0.0;
#pragma unroll
      for (int k = 0; k < 16; ++k) { p1 += acc[k]; p2 = fma(acc[k], acc[k], p2); }
      atomicAdd(&T1R[(size_t)rep * 693 + d], p1);
      atomicAdd(&T2R[(size_t)rep * 693 + d], p2);
    }
  }
}

extern "C" void kernel_launch(void* const* d_in, const int* in_sizes, int n_in,
                              void* d_out, int out_size, void* d_ws, size_t ws_size,
                              hipStream_t stream) {
  (void)out_size;
  float* out = (float*)d_out;   // fp32 outputs (reference returns float32)

  const int want[9] = {196608, 768, 128, 128, 128, 90783, 693, 693, 693};
  bool ok = (n_in == 9);
  for (int i = 0; ok && i < 9; ++i) ok = (in_sizes[i] == want[i]);
  const size_t REQ = 4600000;   // footprint ~4.42 MB (unchanged)
  if (!ok || ws_size < REQ) {
    sentinel_k<<<1, 1, 0, stream>>>(out);
    return;
  }

  const float* xyz = (const float*)d_in[0];
  const float* w1  = (const float*)d_in[1];
  const float* b1  = (const float*)d_in[2];
  const float* g1  = (const float*)d_in[3];
  const float* be1 = (const float*)d_in[4];
  const float* w2  = (const float*)d_in[5];
  const float* b2  = (const float*)d_in[6];
  const float* g2  = (const float*)d_in[7];
  const float* be2 = (const float*)d_in[8];

  // ---- workspace carve (doubles first) ----
  double* S1R = (double*)d_ws;            // 8*128 = 1024
  double* S2R = S1R + 1024;               // 1024
  double* T1R = S2R + 1024;               // 8*693 = 5544
  double* T2R = T1R + 5544;               // 5544
  double* A1  = T2R + 5544;               // 128
  double* B1  = A1 + 128;                 // 128
  double* A2  = B1 + 128;                 // 693
  double* B2  = A2 + 693;                 // 693
  float* l1xyz = (float*)(B2 + 693);      // 4*2048*3 = 24576 f
  float* l2xyz = l1xyz + 24576;           // 4*256*3  = 3072 f
  float* l1pts = l2xyz + 3072;            // 4*2048*128 = 4 MB

  zero_k<<<52, 256, 0, stream>>>(S1R, 13136);

  // FPS: 512 thr, PPG=16 register chunks (regalloc-proven), Morton octant per
  // wave, WAVE-granular exact pruning, lean f32 tail, ring-buffered output.
  fps_k<16, 2048, 8192, 6><<<4, 512, 0, stream>>>(xyz, l1xyz, nullptr);
  fps_k<4, 256, 2048, 3><<<4, 512, 0, stream>>>(l1xyz, l2xyz, out);

  ball1_k<false><<<8192, 256, 0, stream>>>(xyz, l1xyz, w1, b1, nullptr, nullptr,
                                           nullptr, S1R, S2R);
  bn_finalize<<<1, 256, 0, stream>>>(S1R, S2R, 8, 128, 1.0 / (8192.0 * 32.0), g1, be1, A1, B1);
  ball1_k<true><<<8192, 256, 0, stream>>>(xyz, l1xyz, w1, b1, A1, B1,
                                          l1pts, S1R, S2R);

  ball2_k<false><<<1024, 256, 0, stream>>>(l1xyz, l1pts, l2xyz, w2, b2, nullptr, nullptr,
                                           nullptr, T1R, T2R);
  bn_finalize<<<3, 256, 0, stream>>>(T1R, T2R, 8, 693, 1.0 / (1024.0 * 16.0), g2, be2, A2, B2);
  ball2_k<true><<<1024, 256, 0, stream>>>(l1xyz, l1pts, l2xyz, w2, b2, A2, B2,
                                          out + 3072, T1R, T2R);
}

// Round 8
// 4031.568 us; speedup vs baseline: 6.5367x; 1.3572x over previous
//
#include <hip/hip_runtime.h>
#include <hip/hip_bf16.h>

#define DEV __device__ __forceinline__

// ---------- full-wave (64-lane) f32 max, result broadcast via readlane 63 ----------
DEV float wave_max_f32(float v) {
#define STEPDPP(ctrl) { int iv = __float_as_int(v); \
    int sh = __builtin_amdgcn_update_dpp(iv, iv, ctrl, 0xf, 0xf, false); \
    v = fmaxf(v, __int_as_float(sh)); }
  STEPDPP(0x111)  // row_shr:1
  STEPDPP(0x112)  // row_shr:2
  STEPDPP(0x114)  // row_shr:4
  STEPDPP(0x118)  // row_shr:8
  STEPDPP(0x142)  // row_bcast:15
  STEPDPP(0x143)  // row_bcast:31
#undef STEPDPP
  return __int_as_float(__builtin_amdgcn_readlane(__float_as_int(v), 63));
}

// u32 variant (rare tie-refinement path only)
DEV unsigned wave_max_u32(unsigned v) {
#define STEPDPPU(ctrl) { unsigned sh = (unsigned)__builtin_amdgcn_update_dpp((int)v, (int)v, ctrl, 0xf, 0xf, false); \
    v = (sh > v) ? sh : v; }
  STEPDPPU(0x111)
  STEPDPPU(0x112)
  STEPDPPU(0x114)
  STEPDPPU(0x118)
  STEPDPPU(0x142)
  STEPDPPU(0x143)
#undef STEPDPPU
  return (unsigned)__builtin_amdgcn_readlane((int)v, 63);
}

// ---------- sentinel: ws too small / input-shape mismatch ----------
__global__ void sentinel_k(float* out) {
  out[0] = 1000.0f;
}

__global__ __launch_bounds__(256) void zero_k(double* __restrict__ p, int n) {
  int i = blockIdx.x * 256 + threadIdx.x;
  if (i < n) p[i] = 0.0;
}

// ---------- FPS: dense rescan (R0 inner loop) + slim tail + ring output ----------
// Semantics identical to reference _fps: fp32 distances in np op order
// ((dx*dx+dy*dy)+dz*dz), exact fmin chain, argmax with first-(original)-index
// ties. Register layout is index-ordered (thread t owns [t*PPT,(t+1)*PPT)),
// so strict '>' chains + lowest-lane ballot + klo tree give exact min-index
// tie semantics (R0-proven). Changes vs R0 (each proven in passing R5/R7):
//  - f32 DPP wave-max + rare u32 klo tie-refine (replaces u64 DPP chain)
//  - float4 {dist,klo,x,y}+z winner records: ONE dependent LDS round in tail
//  - 128-slot LDS ring output flushed every 64 iters: no global store (and
//    no vmcnt drain) inside the per-iteration barrier
template<int PPT, int NPT, int NPTS, int STRIDE>
__global__ __launch_bounds__(512) void fps_k(const float* __restrict__ pts,
                                             float* __restrict__ out_xyz,
                                             float* __restrict__ out_f) {
  constexpr int NW = 8;                 // 512 threads = 8 waves
  static_assert(NPTS == 512 * PPT, "one chunk per thread");
  const int b = blockIdx.x, t = threadIdx.x;
  const int lane = t & 63, wv = t >> 6;

  __shared__ float4 wkc[2][NW];         // per-wave winner {dist, klo(bits), x, y}
  __shared__ float wz[2][NW];           // per-wave winner z
  __shared__ float ring[128][3];        // batched output ring

  const float* Pb = pts + (size_t)b * NPTS * STRIDE;
  float px[PPT], py[PPT], pz[PPT], dist[PPT];
  const int base = t * PPT;
#pragma unroll
  for (int j = 0; j < PPT; ++j) {
    const float* P = Pb + (size_t)(base + j) * STRIDE;
    px[j] = P[0]; py[j] = P[1]; pz[j] = P[2]; dist[j] = 1e10f;
  }

  // initial centroid = original point 0 (exact input floats; broadcast load)
  float ccx = Pb[0], ccy = Pb[1], ccz = Pb[2];
  if (t == 0) {
    size_t o = (size_t)b * NPT * 3;
    out_xyz[o] = ccx; out_xyz[o + 1] = ccy; out_xyz[o + 2] = ccz;
    if (out_f) { out_f[o] = ccx; out_f[o + 1] = ccy; out_f[o + 2] = ccz; }
  }

  for (int s = 0; s < NPT - 1; ++s) {
    const int p = s & 1;
    // two independent half-chains, exact np op order, strict '>' (first-index
    // tie within chain since register order == index order)
    float vA = -1.0f, vB = -1.0f;
    int jA = 0, jB = PPT / 2;
    float axA = 0.f, ayA = 0.f, azA = 0.f, axB = 0.f, ayB = 0.f, azB = 0.f;
    {
#pragma clang fp contract(off)
#pragma unroll
      for (int j = 0; j < PPT / 2; ++j) {
        float dx = px[j] - ccx, dy = py[j] - ccy, dz = pz[j] - ccz;
        float d = (dx * dx + dy * dy) + dz * dz;     // exact np order, no FMA
        float dj = fminf(dist[j], d);
        dist[j] = dj;
        if (dj > vA) { vA = dj; jA = j; axA = px[j]; ayA = py[j]; azA = pz[j]; }
      }
#pragma unroll
      for (int j = PPT / 2; j < PPT; ++j) {
        float dx = px[j] - ccx, dy = py[j] - ccy, dz = pz[j] - ccz;
        float d = (dx * dx + dy * dy) + dz * dz;
        float dj = fminf(dist[j], d);
        dist[j] = dj;
        if (dj > vB) { vB = dj; jB = j; axB = px[j]; ayB = py[j]; azB = pz[j]; }
      }
    }
    float vmax; int jb; float bx, by, bz;
    if (vB > vA) { vmax = vB; jb = jB; bx = axB; by = ayB; bz = azB; }
    else         { vmax = vA; jb = jA; bx = axA; by = ayA; bz = azA; }
    const unsigned klo = 0xFFFFFFFFu - (unsigned)(base + jb);

    // wave argmax: f32 max; rare exact min-index refine on ties
    float wm = wave_max_f32(vmax);
    unsigned long long mk = __ballot(vmax == wm);
    bool iswin;
    if (mk & (mk - 1)) {                 // tie across lanes (rare)
      unsigned lom = wave_max_u32((vmax == wm) ? klo : 0u);
      iswin = (vmax == wm) && (klo == lom);   // klo unique -> exactly one lane
    } else {
      iswin = (vmax == wm);
    }
    if (iswin) {
      wkc[p][wv] = make_float4(wm, __uint_as_float(klo), bx, by);
      wz[p][wv] = bz;
    }
    __syncthreads();
    // batched output flush (winners j in [s-63, s]); slots disjoint from the
    // concurrent t==0 write to slot (s+1)&127 -> race-free (R5/R7-proven)
    if (s >= 64 && (s & 63) == 0 && t < 192) {
      int j = s - 63 + t / 3, c = t % 3;
      float v = ring[j & 127][c];
      size_t o = ((size_t)b * NPT + j) * 3 + c;
      out_xyz[o] = v;
      if (out_f) out_f[o] = v;
    }
    // tree over 8 wave winners ({dist, klo, x, y} + z: one LDS read round)
    float4 e0 = wkc[p][0], e1 = wkc[p][1], e2 = wkc[p][2], e3 = wkc[p][3];
    float4 e4 = wkc[p][4], e5 = wkc[p][5], e6 = wkc[p][6], e7 = wkc[p][7];
    float z0 = wz[p][0], z1 = wz[p][1], z2 = wz[p][2], z3 = wz[p][3];
    float z4 = wz[p][4], z5 = wz[p][5], z6 = wz[p][6], z7 = wz[p][7];
#define BETTER(A, B) (B.x > A.x || (B.x == A.x && __float_as_uint(B.y) > __float_as_uint(A.y)))
    if (BETTER(e0, e1)) { e0 = e1; z0 = z1; }
    if (BETTER(e2, e3)) { e2 = e3; z2 = z3; }
    if (BETTER(e4, e5)) { e4 = e5; z4 = z5; }
    if (BETTER(e6, e7)) { e6 = e7; z6 = z7; }
    if (BETTER(e0, e2)) { e0 = e2; z0 = z2; }
    if (BETTER(e4, e6)) { e4 = e6; z4 = z6; }
    if (BETTER(e0, e4)) { e0 = e4; z0 = z4; }
#undef BETTER
    ccx = e0.z; ccy = e0.w; ccz = z0;
    if (t == 0) {                        // winner j = s+1 into ring
      int j = s + 1;
      ring[j & 127][0] = ccx; ring[j & 127][1] = ccy; ring[j & 127][2] = ccz;
    }
  }
  // tail flush: winners after the last in-loop flush
  __syncthreads();
  {
    const int rstart = ((NPT - 2) & ~63) + 1;
    const int nf = ((NPT - 1) - rstart + 1) * 3;
    if (t < nf) {
      int j = rstart + t / 3, c = t % 3;
      float v = ring[j & 127][c];
      size_t o = ((size_t)b * NPT + j) * 3 + c;
      out_xyz[o] = v;
      if (out_f) out_f[o] = v;
    }
  }
}

// ---------- layer-1 (fp64 compute, fp32 inputs): ball (first 32 asc) + conv ----------
template<bool APPLY>
__global__ __launch_bounds__(256) void ball1_k(
    const float* __restrict__ xyz, const float* __restrict__ l1xyz,
    const float* __restrict__ w1, const float* __restrict__ b1,
    const double* __restrict__ A1, const double* __restrict__ B1,
    float* __restrict__ l1pts,
    double* __restrict__ S1R, double* __restrict__ S2R) {
  const int blk = blockIdx.x;
  const int b = blk >> 11, s = blk & 2047;
  const int t = threadIdx.x;
  __shared__ double w1s[768];
  __shared__ double b1s[128];
  __shared__ unsigned long long wm[4];
  __shared__ int lst[32];
  __shared__ double fls[32][6];
  __shared__ double red0[128], red1[128];

  for (int i = t; i < 768; i += 256) w1s[i] = (double)w1[i];
  if (t < 128) b1s[t] = (double)b1[t];

  const float* xb = xyz + (size_t)b * 8192 * 6;
  size_t co = ((size_t)b * 2048 + s) * 3;
  double cx = (double)l1xyz[co], cy = (double)l1xyz[co+1], cz = (double)l1xyz[co+2];

  const double R2 = 0.0025 * 0.0025;
  int cnt = 0;
  const int wvv = t >> 6, lane = t & 63;
  {
#pragma clang fp contract(off)
    double cs2 = (cx*cx + cy*cy) + cz*cz;
    for (int chunk = 0; chunk < 32 && cnt < 32; ++chunk) {
      int g = chunk * 256 + t;
      double x = (double)xb[(size_t)g*6];
      double y = (double)xb[(size_t)g*6+1];
      double z = (double)xb[(size_t)g*6+2];
      double pn2 = (x*x + y*y) + z*z;
      double dot = (cx*x + cy*y) + cz*z;
      double dsq = (cs2 + pn2) - 2.0 * dot;    // exact ref formula/order
      bool pred = !(dsq > R2);
      unsigned long long m = __ballot(pred);
      if (lane == 0) wm[wvv] = m;
      __syncthreads();
      int pre = 0, tot = 0;
      for (int w = 0; w < 4; ++w) {
        int c = __popcll(wm[w]);
        if (w < wvv) pre += c;
        tot += c;
      }
      if (pred) {
        int rank = cnt + pre + __popcll(m & ((1ull << lane) - 1ull));
        if (rank < 32) lst[rank] = g;
      }
      cnt += tot;
      __syncthreads();
    }
  }
  int cc = cnt < 32 ? cnt : 32;
  if (t >= cc && t < 32) lst[t] = lst[0];   // pad with first (center in own ball)
  __syncthreads();
  if (t < 32) {
    int j = lst[t];
    fls[t][0] = (double)xb[(size_t)j*6]   - cx;
    fls[t][1] = (double)xb[(size_t)j*6+1] - cy;
    fls[t][2] = (double)xb[(size_t)j*6+2] - cz;
    fls[t][3] = (double)xb[(size_t)j*6+3];
    fls[t][4] = (double)xb[(size_t)j*6+4];
    fls[t][5] = (double)xb[(size_t)j*6+5];
  }
  __syncthreads();
  const int d = t & 127, kh = t >> 7;
  if (APPLY) {
    double a = A1[d], bb = B1[d];
    double vmax = -1e300;
    for (int k = kh; k < 32; k += 2) {
      double h = b1s[d];
#pragma unroll
      for (int c = 0; c < 6; ++c) h = fma(fls[k][c], w1s[c*128 + d], h);
      vmax = fmax(vmax, fma(a, h, bb));
    }
    if (kh == 1) red0[d] = vmax;
    __syncthreads();
    if (kh == 0) {
      double v = fmax(vmax, red0[d]);
      l1pts[((size_t)b * 2048 + s) * 128 + d] = (float)fmax(v, 0.0);
    }
  } else {
    double p1 = 0.0, p2 = 0.0;
    for (int k = kh; k < 32; k += 2) {
      double h = b1s[d];
#pragma unroll
      for (int c = 0; c < 6; ++c) h = fma(fls[k][c], w1s[c*128 + d], h);
      p1 += h; p2 = fma(h, h, p2);
    }
    if (kh == 1) { red0[d] = p1; red1[d] = p2; }
    __syncthreads();
    if (kh == 0) {
      int rep = blk & 7;
      atomicAdd(&S1R[(size_t)rep * 128 + d], p1 + red0[d]);
      atomicAdd(&S2R[(size_t)rep * 128 + d], p2 + red1[d]);
    }
  }
}

// ---------- BN finalize (fp64): A=g/sqrt(var+eps), B=be-mu*A ----------
__global__ __launch_bounds__(256) void bn_finalize(const double* __restrict__ S1,
                                                   const double* __restrict__ S2,
                                                   int nrep, int D, double invN,
                                                   const float* __restrict__ g,
                                                   const float* __restrict__ be,
                                                   double* __restrict__ A, double* __restrict__ Bc) {
  int d = blockIdx.x * 256 + threadIdx.x;
  if (d >= D) return;
  double s1 = 0.0, s2 = 0.0;
  for (int r = 0; r < nrep; ++r) {
    s1 += S1[(size_t)r * D + d];
    s2 += S2[(size_t)r * D + d];
  }
  double mu = s1 * invN;
  double var = s2 * invN - mu * mu;
  double a = (double)g[d] / sqrt(var + 1e-5);
  A[d]  = a;
  Bc[d] = (double)be[d] - mu * a;
}

// ---------- layer-2 (fp64): ball (first 16 asc) + conv(131->693); stats / apply ----------
template<bool APPLY>
__global__ __launch_bounds__(256) void ball2_k(
    const float* __restrict__ l1xyz, const float* __restrict__ l1pts,
    const float* __restrict__ l2xyz,
    const float* __restrict__ w2, const float* __restrict__ b2,
    const double* __restrict__ A2, const double* __restrict__ B2,
    float* __restrict__ outp,
    double* __restrict__ T1R, double* __restrict__ T2R) {
  const int blk = blockIdx.x;
  const int b = blk >> 8, s = blk & 255;
  const int t = threadIdx.x;
  __shared__ double fT[131][16];
  __shared__ unsigned long long wm[4];
  __shared__ int lst[16];
  const float* Pb = l1xyz + (size_t)b * 2048 * 3;
  size_t co = ((size_t)b * 256 + s) * 3;
  double cx = (double)l2xyz[co], cy = (double)l2xyz[co+1], cz = (double)l2xyz[co+2];
  const double R2 = 0.005 * 0.005;
  int cnt = 0;
  const int wvv = t >> 6, lane = t & 63;
  {
#pragma clang fp contract(off)
    double cs2 = (cx*cx + cy*cy) + cz*cz;
    for (int chunk = 0; chunk < 8 && cnt < 16; ++chunk) {
      int g = chunk * 256 + t;
      double x = (double)Pb[(size_t)g*3];
      double y = (double)Pb[(size_t)g*3+1];
      double z = (double)Pb[(size_t)g*3+2];
      double pn2 = (x*x + y*y) + z*z;
      double dot = (cx*x + cy*y) + cz*z;
      double dsq = (cs2 + pn2) - 2.0 * dot;
      bool pred = !(dsq > R2);
      unsigned long long m = __ballot(pred);
      if (lane == 0) wm[wvv] = m;
      __syncthreads();
      int pre = 0, tot = 0;
      for (int w = 0; w < 4; ++w) {
        int c = __popcll(wm[w]);
        if (w < wvv) pre += c;
        tot += c;
      }
      if (pred) {
        int rank = cnt + pre + __popcll(m & ((1ull << lane) - 1ull));
        if (rank < 16) lst[rank] = g;
      }
      cnt += tot;
      __syncthreads();
    }
  }
  int cc = cnt < 16 ? cnt : 16;
  if (t >= cc && t < 16) lst[t] = lst[0];
  __syncthreads();
  for (int i = t; i < 16 * 131; i += 256) {
    int k = i & 15, c = i >> 4;
    int j = lst[k];
    double v;
    if (c == 0)      v = (double)Pb[(size_t)j*3]   - cx;
    else if (c == 1) v = (double)Pb[(size_t)j*3+1] - cy;
    else if (c == 2) v = (double)Pb[(size_t)j*3+2] - cz;
    else             v = (double)l1pts[((size_t)b*2048 + j)*128 + (c-3)];
    fT[c][k] = v;
  }
  __syncthreads();
  const int rep = blk & 7;
  for (int dd = 0; dd < 3; ++dd) {
    int d = t + dd * 256;
    if (d >= 693) break;
    double acc[16];
    double bv = (double)b2[d];
#pragma unroll
    for (int k = 0; k < 16; ++k) acc[k] = bv;
    for (int c = 0; c < 131; ++c) {
      double wv2 = (double)w2[(size_t)c * 693 + d];
#pragma unroll
      for (int k = 0; k < 16; ++k) acc[k] = fma(fT[c][k], wv2, acc[k]);
    }
    if (APPLY) {
      double a = A2[d], bb = B2[d];
      double vmax = -1e300;
#pragma unroll
      for (int k = 0; k < 16; ++k) vmax = fmax(vmax, fma(a, acc[k], bb));
      outp[((size_t)b * 256 + s) * 693 + d] = (float)fmax(vmax, 0.0);
    } else {
      double p1 = 0.0, p2 = 0.0;
#pragma unroll
      for (int k = 0; k < 16; ++k) { p1 += acc[k]; p2 = fma(acc[k], acc[k], p2); }
      atomicAdd(&T1R[(size_t)rep * 693 + d], p1);
      atomicAdd(&T2R[(size_t)rep * 693 + d], p2);
    }
  }
}

extern "C" void kernel_launch(void* const* d_in, const int* in_sizes, int n_in,
                              void* d_out, int out_size, void* d_ws, size_t ws_size,
                              hipStream_t stream) {
  (void)out_size;
  float* out = (float*)d_out;   // fp32 outputs (reference returns float32)

  const int want[9] = {196608, 768, 128, 128, 128, 90783, 693, 693, 693};
  bool ok = (n_in == 9);
  for (int i = 0; ok && i < 9; ++i) ok = (in_sizes[i] == want[i]);
  const size_t REQ = 4600000;   // footprint ~4.42 MB (unchanged)
  if (!ok || ws_size < REQ) {
    sentinel_k<<<1, 1, 0, stream>>>(out);
    return;
  }

  const float* xyz = (const float*)d_in[0];
  const float* w1  = (const float*)d_in[1];
  const float* b1  = (const float*)d_in[2];
  const float* g1  = (const float*)d_in[3];
  const float* be1 = (const float*)d_in[4];
  const float* w2  = (const float*)d_in[5];
  const float* b2  = (const float*)d_in[6];
  const float* g2  = (const float*)d_in[7];
  const float* be2 = (const float*)d_in[8];

  // ---- workspace carve (doubles first) ----
  double* S1R = (double*)d_ws;            // 8*128 = 1024
  double* S2R = S1R + 1024;               // 1024
  double* T1R = S2R + 1024;               // 8*693 = 5544
  double* T2R = T1R + 5544;               // 5544
  double* A1  = T2R + 5544;               // 128
  double* B1  = A1 + 128;                 // 128
  double* A2  = B1 + 128;                 // 693
  double* B2  = A2 + 693;                 // 693
  float* l1xyz = (float*)(B2 + 693);      // 4*2048*3 = 24576 f
  float* l2xyz = l1xyz + 24576;           // 4*256*3  = 3072 f
  float* l1pts = l2xyz + 3072;            // 4*2048*128 = 4 MB

  zero_k<<<52, 256, 0, stream>>>(S1R, 13136);

  // FPS: R0 dense structure + slim tail + ring output (no store drain in loop).
  fps_k<16, 2048, 8192, 6><<<4, 512, 0, stream>>>(xyz, l1xyz, nullptr);
  fps_k<4, 256, 2048, 3><<<4, 512, 0, stream>>>(l1xyz, l2xyz, out);

  ball1_k<false><<<8192, 256, 0, stream>>>(xyz, l1xyz, w1, b1, nullptr, nullptr,
                                           nullptr, S1R, S2R);
  bn_finalize<<<1, 256, 0, stream>>>(S1R, S2R, 8, 128, 1.0 / (8192.0 * 32.0), g1, be1, A1, B1);
  ball1_k<true><<<8192, 256, 0, stream>>>(xyz, l1xyz, w1, b1, A1, B1,
                                          l1pts, S1R, S2R);

  ball2_k<false><<<1024, 256, 0, stream>>>(l1xyz, l1pts, l2xyz, w2, b2, nullptr, nullptr,
                                           nullptr, T1R, T2R);
  bn_finalize<<<3, 256, 0, stream>>>(T1R, T2R, 8, 693, 1.0 / (1024.0 * 16.0), g2, be2, A2, B2);
  ball2_k<true><<<1024, 256, 0, stream>>>(l1xyz, l1pts, l2xyz, w2, b2, A2, B2,
                                          out + 3072, T1R, T2R);
}